// Round 2
// baseline (204.529 us; speedup 1.0000x reference)
//
#include <hip/hip_runtime.h>

#define B 2
#define S 2048
#define D 512
#define H 8
#define KD 64

typedef __bf16 bf16_t;
typedef __bf16 bf16x8 __attribute__((ext_vector_type(8)));
typedef __bf16 bf16x4 __attribute__((ext_vector_type(4)));
typedef float f32x4 __attribute__((ext_vector_type(4)));

// Swizzled byte offset into a [64 rows][512 cols] bf16 LDS tile.
// Row-linear 1 KB rows; XOR of (row&7) into the 16B-slot bits makes a wave's
// 64-lane ds_read_b128 (16 rows x 4 col-groups) hit the 8-phase floor with
// all 32 banks busy each phase (G4).
__device__ __forceinline__ int swz(int row, int col) {
    return row * 1024 + ((col * 2) ^ ((row & 7) << 4));
}

// ---------------------------------------------------------------------------
// Kernel 1: fused QKV projection. out = (X @ W[h] + b[h]) * scale.
// W[h] (512x64 f32) staged once per block into LDS as bf16 [col][d] swizzled;
// B-fragments are then single ds_read_b128s.
// grid = (16 bh * 8 sgroups, 3 mats), block 256 (4 waves); each block does
// 4 s-tiles of 64 rows (256 rows) against its staged W.
// ---------------------------------------------------------------------------
__global__ __launch_bounds__(256) void qkv_kernel(
    const float* __restrict__ q_in, const float* __restrict__ k_in, const float* __restrict__ v_in,
    const float* __restrict__ Wq, const float* __restrict__ Wk, const float* __restrict__ Wv,
    const float* __restrict__ bq, const float* __restrict__ bk, const float* __restrict__ bv,
    bf16_t* __restrict__ Qo, bf16_t* __restrict__ Ko, bf16_t* __restrict__ VTo)
{
    __shared__ char wt[64 * 1024];

    const int mat = blockIdx.y;
    const float* Xp   = (mat == 0) ? q_in : (mat == 1) ? k_in : v_in;
    const float* Wp   = (mat == 0) ? Wq   : (mat == 1) ? Wk   : Wv;
    const float* bias = (mat == 0) ? bq   : (mat == 1) ? bk   : bv;
    const float scale = (mat == 0) ? 0.125f : 1.0f;   // 1/sqrt(64) folded into Q

    const int sg = blockIdx.x & 7;
    const int bh = blockIdx.x >> 3;
    const int h = bh & (H - 1), b = bh >> 3;

    const int tid = threadIdx.x;
    const int wave = tid >> 6, lane = tid & 63;
    const int g = lane >> 4, c = lane & 15;

    // ---- stage W[h]: wt[col][d] = (bf16) W[h][d][col] ----
    {
        const int col = tid & 63, kq = tid >> 6;
        const float* wp = Wp + (size_t)h * D * KD + col;
        for (int k = kq; k < D; k += 4)
            *reinterpret_cast<bf16_t*>(wt + swz(col, k)) = (bf16_t)wp[(size_t)k * KD];
    }
    __syncthreads();

    for (int st = 0; st < 4; ++st) {
        const int row0 = (sg * 4 + st) * 64 + wave * 16;
        const float* xrow = Xp + ((size_t)b * S + row0 + c) * D;
        const f32x4 zero = {0.f, 0.f, 0.f, 0.f};
        f32x4 acc[4] = {zero, zero, zero, zero};

        for (int k0 = 0; k0 < D; k0 += 32) {
            bf16x8 a;
            const float4 f0 = *reinterpret_cast<const float4*>(xrow + k0 + g * 8);
            const float4 f1 = *reinterpret_cast<const float4*>(xrow + k0 + g * 8 + 4);
            a[0] = (bf16_t)f0.x; a[1] = (bf16_t)f0.y; a[2] = (bf16_t)f0.z; a[3] = (bf16_t)f0.w;
            a[4] = (bf16_t)f1.x; a[5] = (bf16_t)f1.y; a[6] = (bf16_t)f1.z; a[7] = (bf16_t)f1.w;
#pragma unroll
            for (int ct = 0; ct < 4; ++ct) {
                const bf16x8 wf = *reinterpret_cast<const bf16x8*>(wt + swz(ct * 16 + c, k0 + g * 8));
                acc[ct] = __builtin_amdgcn_mfma_f32_16x16x32_bf16(a, wf, acc[ct], 0, 0, 0);
            }
        }

#pragma unroll
        for (int ct = 0; ct < 4; ++ct) {
            const int col = ct * 16 + c;
            const float bval = bias[h * KD + col];
#pragma unroll
            for (int i = 0; i < 4; ++i) {
                const int r = row0 + g * 4 + i;
                const float v = (acc[ct][i] + bval) * scale;
                if (mat == 0)      Qo[((size_t)bh * S + r) * KD + col] = (bf16_t)v;
                else if (mat == 1) Ko[((size_t)bh * S + r) * KD + col] = (bf16_t)v;
                else               VTo[((size_t)bh * KD + col) * S + r] = (bf16_t)v;
            }
        }
    }
}

// ---------------------------------------------------------------------------
// Kernel 2: flash attention, swapped-operand form. grid = B*H*(S/64), 4 waves.
// Wave owns 16 q-rows. Per 32-KV tile:
//   S^T = mfma(K_perm, Q): D-layout col = q = lane&15, so the lane's 8 scores
//   all belong to ONE q-row. K rows are permuted (row r of MFMA t -> kv
//   8*(r>>2)+4t+(r&3)) so the lane holds exactly kv = 8g..8g+7 -> the PV
//   B-fragment is formed IN-REGISTER (no LDS, no cross-lane repack).
//   m/l are per-lane scalars; only the tile max needs 2 shuffles; the sum
//   reduce is deferred to after the loop. PV accumulates ctx^T.
// ---------------------------------------------------------------------------
__global__ __launch_bounds__(256) void attn_kernel(
    const bf16_t* __restrict__ Q,   // [BH, S, 64]
    const bf16_t* __restrict__ Km,  // [BH, S, 64]
    const bf16_t* __restrict__ VT,  // [BH, 64, S]
    bf16_t* __restrict__ CTX)       // [B, S, H*64]
{
    const int stile = blockIdx.x & 31;
    const int bh    = blockIdx.x >> 5;
    const int b = bh >> 3, h = bh & (H - 1);

    const int tid = threadIdx.x;
    const int wave = tid >> 6, lane = tid & 63;
    const int g = lane >> 4, c = lane & 15;
    const int q0 = stile * 64 + wave * 16;

    // Q as the B-operand (col = q-row = c): same fragment as a plain A-load.
    const bf16_t* qp = Q + ((size_t)bh * S + q0 + c) * KD;
    const bf16x8 qlo = *reinterpret_cast<const bf16x8*>(qp + g * 8);
    const bf16x8 qhi = *reinterpret_cast<const bf16x8*>(qp + 32 + g * 8);

    // K-row permutation: MFMA t, A-row c -> kv = 8*(c>>2) + 4t + (c&3)
    const int kvA = 8 * (c >> 2) + (c & 3);
    const int kvB = kvA + 4;
    const bf16_t* kbase = Km + (size_t)bh * S * KD;
    const bf16_t* vbase = VT + (size_t)bh * KD * S;

    const f32x4 zero = {0.f, 0.f, 0.f, 0.f};
    f32x4 acc[4] = {zero, zero, zero, zero};   // acc[ct][i] = ctx[q0+c][ct*16+4g+i]
    float m_run = -1e30f, l_run = 0.f;

    // double-buffered K/V fragment registers
    bf16x8 kc[4], vc[4];
    {
        const bf16_t* kr0 = kbase + (size_t)kvA * KD + g * 8;
        const bf16_t* kr1 = kbase + (size_t)kvB * KD + g * 8;
        kc[0] = *reinterpret_cast<const bf16x8*>(kr0);
        kc[1] = *reinterpret_cast<const bf16x8*>(kr0 + 32);
        kc[2] = *reinterpret_cast<const bf16x8*>(kr1);
        kc[3] = *reinterpret_cast<const bf16x8*>(kr1 + 32);
#pragma unroll
        for (int ct = 0; ct < 4; ++ct)
            vc[ct] = *reinterpret_cast<const bf16x8*>(vbase + (size_t)(ct * 16 + c) * S + g * 8);
    }

    for (int kv0 = 0; kv0 < S; kv0 += 32) {
        // ---- prefetch next tile (wraps harmlessly on the last iteration) ----
        const int nxt = (kv0 + 32) & (S - 1);
        bf16x8 kn[4], vn[4];
        {
            const bf16_t* kr0 = kbase + (size_t)(nxt + kvA) * KD + g * 8;
            const bf16_t* kr1 = kbase + (size_t)(nxt + kvB) * KD + g * 8;
            kn[0] = *reinterpret_cast<const bf16x8*>(kr0);
            kn[1] = *reinterpret_cast<const bf16x8*>(kr0 + 32);
            kn[2] = *reinterpret_cast<const bf16x8*>(kr1);
            kn[3] = *reinterpret_cast<const bf16x8*>(kr1 + 32);
#pragma unroll
            for (int ct = 0; ct < 4; ++ct)
                vn[ct] = *reinterpret_cast<const bf16x8*>(vbase + (size_t)(ct * 16 + c) * S + nxt + g * 8);
        }

        // ---- S^T: lane holds s0[i] at kv0+8g+i, s1[i] at kv0+8g+4+i, q = q0+c
        f32x4 s0 = zero, s1 = zero;
        s0 = __builtin_amdgcn_mfma_f32_16x16x32_bf16(kc[0], qlo, s0, 0, 0, 0);
        s0 = __builtin_amdgcn_mfma_f32_16x16x32_bf16(kc[1], qhi, s0, 0, 0, 0);
        s1 = __builtin_amdgcn_mfma_f32_16x16x32_bf16(kc[2], qlo, s1, 0, 0, 0);
        s1 = __builtin_amdgcn_mfma_f32_16x16x32_bf16(kc[3], qhi, s1, 0, 0, 0);

        // ---- row max: 7 in-lane + 2 shuffles (lanes {c, c+16, c+32, c+48})
        float pm = fmaxf(fmaxf(fmaxf(s0[0], s0[1]), fmaxf(s0[2], s0[3])),
                         fmaxf(fmaxf(s1[0], s1[1]), fmaxf(s1[2], s1[3])));
        pm = fmaxf(pm, __shfl_xor(pm, 16));
        pm = fmaxf(pm, __shfl_xor(pm, 32));

        const float mn = fmaxf(m_run, pm);
        const float f = __expf(m_run - mn);
        m_run = mn;

        const float p0 = __expf(s0[0] - mn), p1 = __expf(s0[1] - mn);
        const float p2 = __expf(s0[2] - mn), p3 = __expf(s0[3] - mn);
        const float p4 = __expf(s1[0] - mn), p5 = __expf(s1[1] - mn);
        const float p6 = __expf(s1[2] - mn), p7 = __expf(s1[3] - mn);
        l_run = l_run * f + (((p0 + p1) + (p2 + p3)) + ((p4 + p5) + (p6 + p7)));

        bf16x8 pp;   // the PV B-fragment, directly: pp[j] = P[q0+c][kv0+8g+j]
        pp[0] = (bf16_t)p0; pp[1] = (bf16_t)p1; pp[2] = (bf16_t)p2; pp[3] = (bf16_t)p3;
        pp[4] = (bf16_t)p4; pp[5] = (bf16_t)p5; pp[6] = (bf16_t)p6; pp[7] = (bf16_t)p7;

#pragma unroll
        for (int ct = 0; ct < 4; ++ct) acc[ct] = acc[ct] * f;
#pragma unroll
        for (int ct = 0; ct < 4; ++ct)
            acc[ct] = __builtin_amdgcn_mfma_f32_16x16x32_bf16(vc[ct], pp, acc[ct], 0, 0, 0);

#pragma unroll
        for (int j = 0; j < 4; ++j) { kc[j] = kn[j]; vc[j] = vn[j]; }
    }

    // deferred sum reduce (once) + normalize + store ctx (bf16, head-concat)
    l_run += __shfl_xor(l_run, 16);
    l_run += __shfl_xor(l_run, 32);
    const float inv = 1.0f / l_run;

#pragma unroll
    for (int ct = 0; ct < 4; ++ct) {
        bf16x4 o;
        o[0] = (bf16_t)(acc[ct][0] * inv); o[1] = (bf16_t)(acc[ct][1] * inv);
        o[2] = (bf16_t)(acc[ct][2] * inv); o[3] = (bf16_t)(acc[ct][3] * inv);
        *reinterpret_cast<bf16x4*>(&CTX[((size_t)b * S + q0 + c) * (H * KD) + h * KD + ct * 16 + 4 * g]) = o;
    }
}

// ---------------------------------------------------------------------------
// Kernel 3: output projection. out = CTX[4096x512](bf16) @ Wo[512x512] + bo.
// Wo column-slice staged as bf16 in swizzled LDS (same layout as qkv).
// grid = 64 mtiles * 8 ntiles = 512 blocks, block 256.
// ---------------------------------------------------------------------------
__global__ __launch_bounds__(256) void out_proj_kernel(
    const bf16_t* __restrict__ CTX,
    const float* __restrict__ Wo,
    const float* __restrict__ bo,
    float* __restrict__ out)
{
    __shared__ char wt[64 * 1024];

    const int ntile = blockIdx.x & 7;
    const int mtile = blockIdx.x >> 3;
    const int n0 = ntile * 64;

    const int tid = threadIdx.x;
    const int wave = tid >> 6, lane = tid & 63;
    const int g = lane >> 4, c = lane & 15;

    // stage Wo[:, n0:n0+64]: wt[col][k] = (bf16) Wo[k][n0+col]
    {
        const int col = tid & 63, kq = tid >> 6;
        for (int k = kq; k < D; k += 4)
            *reinterpret_cast<bf16_t*>(wt + swz(col, k)) = (bf16_t)Wo[(size_t)k * D + n0 + col];
    }
    __syncthreads();

    const int row0 = mtile * 64 + wave * 16;
    const f32x4 zero = {0.f, 0.f, 0.f, 0.f};
    f32x4 acc[4] = {zero, zero, zero, zero};

    const bf16_t* arow = CTX + (size_t)(row0 + c) * (H * KD);
    for (int k0 = 0; k0 < H * KD; k0 += 32) {
        const bf16x8 a = *reinterpret_cast<const bf16x8*>(arow + k0 + g * 8);
#pragma unroll
        for (int ct = 0; ct < 4; ++ct) {
            const bf16x8 wf = *reinterpret_cast<const bf16x8*>(wt + swz(ct * 16 + c, k0 + g * 8));
            acc[ct] = __builtin_amdgcn_mfma_f32_16x16x32_bf16(a, wf, acc[ct], 0, 0, 0);
        }
    }

#pragma unroll
    for (int ct = 0; ct < 4; ++ct) {
        const int col = n0 + ct * 16 + c;
        const float bval = bo[col];
#pragma unroll
        for (int i = 0; i < 4; ++i)
            out[(size_t)(row0 + g * 4 + i) * D + col] = acc[ct][i] + bval;
    }
}

// ---------------------------------------------------------------------------
extern "C" void kernel_launch(void* const* d_in, const int* in_sizes, int n_in,
                              void* d_out, int out_size, void* d_ws, size_t ws_size,
                              hipStream_t stream) {
    const float* query = (const float*)d_in[0];
    const float* key_  = (const float*)d_in[1];
    const float* value = (const float*)d_in[2];
    const float* Wq = (const float*)d_in[3];
    const float* bq = (const float*)d_in[4];
    const float* Wk = (const float*)d_in[5];
    const float* bk = (const float*)d_in[6];
    const float* Wv = (const float*)d_in[7];
    const float* bv = (const float*)d_in[8];
    const float* Wo = (const float*)d_in[9];
    const float* bo = (const float*)d_in[10];
    float* out = (float*)d_out;

    const size_t nPerMat = (size_t)B * H * S * KD;   // 4 MB bf16 each
    bf16_t* Qw   = (bf16_t*)d_ws;
    bf16_t* Kw   = Qw + nPerMat;
    bf16_t* VTw  = Kw + nPerMat;
    bf16_t* CTXw = VTw + nPerMat;                    // total 16 MB of ws

    dim3 grid1(16 * 8, 3);
    qkv_kernel<<<grid1, 256, 0, stream>>>(query, key_, value, Wq, Wk, Wv,
                                          bq, bk, bv, Qw, Kw, VTw);
    attn_kernel<<<B * H * (S / 64), 256, 0, stream>>>(Qw, Kw, VTw, CTXw);
    out_proj_kernel<<<(B * S / 64) * (D / 64), 256, 0, stream>>>(CTXw, Wo, bo, out);
}

// Round 3
// 100.445 us; speedup vs baseline: 2.0362x; 2.0362x over previous
//
#include <hip/hip_runtime.h>

#define B 2
#define S 2048
#define D 512
#define H 8
#define KD 64

typedef __bf16 bf16_t;
typedef __bf16 bf16x8 __attribute__((ext_vector_type(8)));
typedef __bf16 bf16x4 __attribute__((ext_vector_type(4)));
typedef float f32x4 __attribute__((ext_vector_type(4)));

#define QSCALE 0.1803368801111204f   /* 0.125 * log2(e): exp2-domain softmax */

__device__ __forceinline__ void async_copy16(const void* g, void* l) {
    __builtin_amdgcn_global_load_lds(
        (const __attribute__((address_space(1))) void*)g,
        (__attribute__((address_space(3))) void*)l, 16, 0, 0);
}

// ---------------------------------------------------------------------------
// Kernel 0: weight prep. Transpose+convert once:
//   Wt{q,k,v}[h][col(64)][d(512)] bf16  <-  W*[h][d][col] f32
//   WoT[n(512)][k(512)]        bf16  <-  Wo[k][n] f32
// 256 blocks x 256 thr; 64x64 LDS tile transpose each.
// ---------------------------------------------------------------------------
__global__ __launch_bounds__(256) void prep_kernel(
    const float* __restrict__ Wq, const float* __restrict__ Wk,
    const float* __restrict__ Wv, const float* __restrict__ Wo,
    bf16_t* __restrict__ Wtq, bf16_t* __restrict__ Wtk,
    bf16_t* __restrict__ Wtv, bf16_t* __restrict__ WoT)
{
    __shared__ bf16_t tl[64][72];
    const int blk = blockIdx.x, t = threadIdx.x;

    const float* src; bf16_t* dstbase;
    int ld, r0, c0;
    if (blk < 192) {                       // Wq/Wk/Wv
        const int mat = blk >> 6, h = (blk & 63) >> 3, dt = blk & 7;
        const float* W = (mat == 0) ? Wq : (mat == 1) ? Wk : Wv;
        bf16_t* Wt = (mat == 0) ? Wtq : (mat == 1) ? Wtk : Wtv;
        src = W + (size_t)h * D * KD; dstbase = Wt + (size_t)h * KD * D;
        ld = KD; r0 = dt * 64; c0 = 0;
    } else {                               // Wo
        const int kt = (blk - 192) >> 3, nt = (blk - 192) & 7;
        src = Wo; dstbase = WoT;
        ld = D; r0 = kt * 64; c0 = nt * 64;
    }

    { // phase 1: read f32 rows, convert, store to LDS [row][col]
        const int r = t >> 2, cq = (t & 3) * 16;
        const float* sp = src + (size_t)(r0 + r) * ld + c0 + cq;
#pragma unroll
        for (int q = 0; q < 4; ++q) {
            const float4 f = *reinterpret_cast<const float4*>(sp + q * 4);
            tl[r][cq + q * 4 + 0] = (bf16_t)f.x; tl[r][cq + q * 4 + 1] = (bf16_t)f.y;
            tl[r][cq + q * 4 + 2] = (bf16_t)f.z; tl[r][cq + q * 4 + 3] = (bf16_t)f.w;
        }
    }
    __syncthreads();
    { // phase 2: gather transposed, 16B stores
        const int cc = t >> 2, rq = (t & 3) * 16;
        bf16x8 o0, o1;
#pragma unroll
        for (int j = 0; j < 8; ++j) { o0[j] = tl[rq + j][cc]; o1[j] = tl[rq + 8 + j][cc]; }
        bf16_t* dp = dstbase + (size_t)(c0 + cc) * 512 + r0 + rq;
        *reinterpret_cast<bf16x8*>(dp) = o0;
        *reinterpret_cast<bf16x8*>(dp + 8) = o1;
    }
}

// ---------------------------------------------------------------------------
// Kernel 1: fused QKV projection. Wt[h] (64KB bf16) staged via global_load_lds
// with pre-swizzled source; B-frags are single swizzled ds_read_b128.
// grid = (16bh x 32 stiles, 3 mats), 256 thr (4 waves x 16 rows).
// Q gets scale 0.125*log2e folded in.
// ---------------------------------------------------------------------------
__global__ __launch_bounds__(256) void qkv_kernel(
    const float* __restrict__ q_in, const float* __restrict__ k_in, const float* __restrict__ v_in,
    const bf16_t* __restrict__ Wtq, const bf16_t* __restrict__ Wtk, const bf16_t* __restrict__ Wtv,
    const float* __restrict__ bq, const float* __restrict__ bk, const float* __restrict__ bv,
    bf16_t* __restrict__ Qo, bf16_t* __restrict__ Ko, bf16_t* __restrict__ VTo)
{
    __shared__ char wlds[65536];

    const int mat = blockIdx.y;
    const float* Xp     = (mat == 0) ? q_in : (mat == 1) ? k_in : v_in;
    const bf16_t* Wt    = (mat == 0) ? Wtq  : (mat == 1) ? Wtk  : Wtv;
    const float* bias   = (mat == 0) ? bq   : (mat == 1) ? bk   : bv;
    const float scale   = (mat == 0) ? QSCALE : 1.0f;

    const int stile = blockIdx.x & 31;
    const int bh    = blockIdx.x >> 5;
    const int h = bh & (H - 1), b = bh >> 3;

    const int tid = threadIdx.x, wave = tid >> 6, lane = tid & 63;
    const int g = lane >> 4, c = lane & 15;

    // stage Wt[h]: LDS[col][slot] = W[col][slot ^ (col&7)]  (64 x 1KB rows)
    {
        const bf16_t* wbase = Wt + (size_t)h * (64 * 512);
#pragma unroll
        for (int j = 0; j < 16; ++j) {
            const int col = wave * 16 + j;
            const int ss = lane ^ (col & 7);
            async_copy16(wbase + (size_t)col * 512 + ss * 8, wlds + col * 1024);
        }
    }
    __syncthreads();

    const int row0 = stile * 64 + wave * 16;
    const float* xrow = Xp + ((size_t)b * S + row0 + c) * D;
    const f32x4 zero = {0.f, 0.f, 0.f, 0.f};
    f32x4 acc[4] = {zero, zero, zero, zero};

    for (int k0 = 0; k0 < D; k0 += 32) {
        bf16x8 a;
        const float4 f0 = *reinterpret_cast<const float4*>(xrow + k0 + g * 8);
        const float4 f1 = *reinterpret_cast<const float4*>(xrow + k0 + g * 8 + 4);
        a[0] = (bf16_t)f0.x; a[1] = (bf16_t)f0.y; a[2] = (bf16_t)f0.z; a[3] = (bf16_t)f0.w;
        a[4] = (bf16_t)f1.x; a[5] = (bf16_t)f1.y; a[6] = (bf16_t)f1.z; a[7] = (bf16_t)f1.w;
#pragma unroll
        for (int ct = 0; ct < 4; ++ct) {
            const int col = ct * 16 + c;
            const bf16x8 wf = *reinterpret_cast<const bf16x8*>(
                wlds + col * 1024 + ((k0 * 2 + g * 16) ^ ((col & 7) << 4)));
            acc[ct] = __builtin_amdgcn_mfma_f32_16x16x32_bf16(a, wf, acc[ct], 0, 0, 0);
        }
    }

#pragma unroll
    for (int ct = 0; ct < 4; ++ct) {
        const int col = ct * 16 + c;
        const float bval = bias[h * KD + col];
        if (mat < 2) {
            bf16_t* outp = (mat == 0 ? Qo : Ko);
#pragma unroll
            for (int i = 0; i < 4; ++i) {
                const int r = row0 + g * 4 + i;
                outp[((size_t)bh * S + r) * KD + col] = (bf16_t)((acc[ct][i] + bval) * scale);
            }
        } else {
            bf16x4 o;
#pragma unroll
            for (int i = 0; i < 4; ++i) o[i] = (bf16_t)(acc[ct][i] + bval);
            *reinterpret_cast<bf16x4*>(VTo + ((size_t)bh * KD + col) * S + row0 + 4 * g) = o;
        }
    }
}

// ---------------------------------------------------------------------------
// Kernel 2: flash attention. 256 blocks (XCD-pinned per bh), 512 thr (8 waves
// x 16 q-rows = 128-row Q tile). K/V 64-KV tiles double-buffered in LDS via
// global_load_lds (pre-swizzled source). Swapped QK^T; in-register P; exp2
// softmax with defer-max. ctx written f32 to d_out.
// ---------------------------------------------------------------------------
__global__ __launch_bounds__(512) void attn_kernel(
    const bf16_t* __restrict__ Q,   // [BH, S, 64] (pre-scaled)
    const bf16_t* __restrict__ Km,  // [BH, S, 64]
    const bf16_t* __restrict__ VT,  // [BH, 64, S]
    float* __restrict__ CTX)        // [B*S, 512] f32 (= d_out)
{
    __shared__ char kv_lds[2][16384];   // per buf: K [64][128B] | V [64][128B]

    // XCD-bijective swizzle: all 16 q-tiles of a bh land on one XCD.
    const int hw = blockIdx.x;                 // 256 blocks
    const int xcd = hw & 7, slot = hw >> 3;    // slot 0..31
    const int bh = xcd * 2 + (slot >> 4);
    const int stile = slot & 15;
    const int b = bh >> 3, h = bh & (H - 1);

    const int tid = threadIdx.x, wave = tid >> 6, lane = tid & 63;
    const int g = lane >> 4, c = lane & 15;
    const int q0 = stile * 128 + wave * 16;

    const bf16_t* kg = Km + (size_t)bh * S * KD;
    const bf16_t* vg = VT + (size_t)bh * KD * S;

    // Q fragments (B-operand; col = q-row = c)
    const bf16_t* qp = Q + ((size_t)bh * S + q0 + c) * KD;
    const bf16x8 qlo = *reinterpret_cast<const bf16x8*>(qp + g * 8);
    const bf16x8 qhi = *reinterpret_cast<const bf16x8*>(qp + 32 + g * 8);

    // hoisted swizzled LDS read offsets
    int koff[4][2], voff[4][2];
#pragma unroll
    for (int tt = 0; tt < 4; ++tt) {
        const int row = 8 * (c >> 2) + (c & 3) + 4 * (tt & 1) + 32 * (tt >> 1);
        const int ys = (row & 7) ^ (((row >> 3) & 1) << 2);
        koff[tt][0] = row * 128 + ((g * 16) ^ (ys << 4));
        koff[tt][1] = row * 128 + ((64 + g * 16) ^ (ys << 4));
    }
#pragma unroll
    for (int ct = 0; ct < 4; ++ct) {
        const int row = ct * 16 + c;
        const int ys = (row & 7) ^ (((row >> 3) & 1) << 2);
        voff[ct][0] = 8192 + row * 128 + ((g * 16) ^ (ys << 4));
        voff[ct][1] = 8192 + row * 128 + ((64 + g * 16) ^ (ys << 4));
    }

    // staging lane geometry
    const int srow = lane >> 3, sslot = lane & 7;
    const int kwv = wave & 3;                     // row-group within K or V half
    const int krow0a = kwv * 16, krow0b = kwv * 16 + 8;
    const int rowa = krow0a + srow, rowb = krow0b + srow;
    const int ysa = (rowa & 7) ^ (((rowa >> 3) & 1) << 2);
    const int ysb = (rowb & 7) ^ (((rowb >> 3) & 1) << 2);
    const int ssa = sslot ^ ysa, ssb = sslot ^ ysb;

    const f32x4 zero = {0.f, 0.f, 0.f, 0.f};
    f32x4 acc[4] = {zero, zero, zero, zero};
    float m_run = -1e30f, l_run = 0.f;

#define STAGE(bufidx, kv0)                                                        \
    do {                                                                          \
        char* bp = kv_lds[0] + (bufidx) * 16384;                                  \
        if (wave < 4) {                                                           \
            async_copy16(kg + (size_t)((kv0) + rowa) * KD + ssa * 8, bp + krow0a * 128); \
            async_copy16(kg + (size_t)((kv0) + rowb) * KD + ssb * 8, bp + krow0b * 128); \
        } else {                                                                  \
            async_copy16(vg + (size_t)rowa * S + (kv0) + ssa * 8, bp + 8192 + krow0a * 128); \
            async_copy16(vg + (size_t)rowb * S + (kv0) + ssb * 8, bp + 8192 + krow0b * 128); \
        }                                                                         \
    } while (0)

    STAGE(0, 0);
    __syncthreads();   // drains vmcnt before barrier (compiler-emitted)

    int buf = 0;
    for (int t = 0; t < S / 64; ++t) {
        if (t < S / 64 - 1) STAGE(buf ^ 1, (t + 1) * 64);
        const char* kb = kv_lds[0] + buf * 16384;

        // ---- QK^T (swapped): sc[tt][i] = S[q0+c][kv0 + 8g + i + 4*(tt&1) + 32*(tt>>1)]
        f32x4 sc[4];
#pragma unroll
        for (int tt = 0; tt < 4; ++tt) {
            const bf16x8 k0f = *reinterpret_cast<const bf16x8*>(kb + koff[tt][0]);
            const bf16x8 k1f = *reinterpret_cast<const bf16x8*>(kb + koff[tt][1]);
            f32x4 z = zero;
            z = __builtin_amdgcn_mfma_f32_16x16x32_bf16(k0f, qlo, z, 0, 0, 0);
            sc[tt] = __builtin_amdgcn_mfma_f32_16x16x32_bf16(k1f, qhi, z, 0, 0, 0);
        }

        // ---- softmax (exp2 domain, deferred max)
        const float a0 = fmaxf(fmaxf(sc[0][0], sc[0][1]), fmaxf(sc[0][2], sc[0][3]));
        const float a1 = fmaxf(fmaxf(sc[1][0], sc[1][1]), fmaxf(sc[1][2], sc[1][3]));
        const float a2 = fmaxf(fmaxf(sc[2][0], sc[2][1]), fmaxf(sc[2][2], sc[2][3]));
        const float a3 = fmaxf(fmaxf(sc[3][0], sc[3][1]), fmaxf(sc[3][2], sc[3][3]));
        float pm = fmaxf(fmaxf(a0, a1), fmaxf(a2, a3));
        if (!__all(pm <= m_run + 8.0f)) {
            pm = fmaxf(pm, __shfl_xor(pm, 16));
            pm = fmaxf(pm, __shfl_xor(pm, 32));
            const float mn = fmaxf(m_run, pm);
            const float fs = exp2f(m_run - mn);
            m_run = mn;
            l_run *= fs;
#pragma unroll
            for (int ct = 0; ct < 4; ++ct) acc[ct] = acc[ct] * fs;
        }

        bf16x8 f0, f1;
        float ls = 0.f;
#pragma unroll
        for (int i = 0; i < 4; ++i) {
            const float p0 = exp2f(sc[0][i] - m_run);
            const float p1 = exp2f(sc[1][i] - m_run);
            const float p2 = exp2f(sc[2][i] - m_run);
            const float p3 = exp2f(sc[3][i] - m_run);
            f0[i] = (bf16_t)p0; f0[4 + i] = (bf16_t)p1;
            f1[i] = (bf16_t)p2; f1[4 + i] = (bf16_t)p3;
            ls += (p0 + p1) + (p2 + p3);
        }
        l_run += ls;

        // ---- PV: acc[ct] += V^T rows (d) x P
#pragma unroll
        for (int ct = 0; ct < 4; ++ct) {
            const bf16x8 v0f = *reinterpret_cast<const bf16x8*>(kb + voff[ct][0]);
            const bf16x8 v1f = *reinterpret_cast<const bf16x8*>(kb + voff[ct][1]);
            acc[ct] = __builtin_amdgcn_mfma_f32_16x16x32_bf16(v0f, f0, acc[ct], 0, 0, 0);
            acc[ct] = __builtin_amdgcn_mfma_f32_16x16x32_bf16(v1f, f1, acc[ct], 0, 0, 0);
        }

        __syncthreads();   // staged buf^1 complete + all reads of buf done
        buf ^= 1;
    }
#undef STAGE

    // ---- finalize: fold l across the 4 g-lanes of each q, write f32 ctx
    l_run += __shfl_xor(l_run, 16);
    l_run += __shfl_xor(l_run, 32);
    const float inv = 1.0f / l_run;

    float* op = CTX + ((size_t)b * S + q0 + c) * 512 + h * 64;
#pragma unroll
    for (int ct = 0; ct < 4; ++ct) {
        float4 o;
        o.x = acc[ct][0] * inv; o.y = acc[ct][1] * inv;
        o.z = acc[ct][2] * inv; o.w = acc[ct][3] * inv;
        *reinterpret_cast<float4*>(op + ct * 16 + 4 * g) = o;
    }
}

// ---------------------------------------------------------------------------
// Kernel 3: output projection, in place on d_out.
//   out[r][n] = sum_k ctx[r][k] * WoT[n][k] + bo[n]
// 256 blocks x 16 rows; 2 waves split n in halves. Each wave loads its A-rows
// fully into registers, then one barrier makes read->write in-place safe.
// ---------------------------------------------------------------------------
__global__ __launch_bounds__(128) void out_proj_kernel(
    const float* __restrict__ CTXf,   // = d_out
    const bf16_t* __restrict__ WoT,   // [512 n][512 k]
    const float* __restrict__ bo,
    float* __restrict__ out)          // = d_out
{
    const int mtile = blockIdx.x;                 // 0..255, 16 rows each
    const int tid = threadIdx.x, nh = tid >> 6, lane = tid & 63;
    const int g = lane >> 4, c = lane & 15;
    const int row0 = mtile * 16;

    // A-rows into registers (16 ksteps)
    bf16x8 afr[16];
    const float* arow = CTXf + (size_t)(row0 + c) * 512;
#pragma unroll
    for (int ks = 0; ks < 16; ++ks) {
        const float4 f0 = *reinterpret_cast<const float4*>(arow + ks * 32 + g * 8);
        const float4 f1 = *reinterpret_cast<const float4*>(arow + ks * 32 + g * 8 + 4);
        bf16x8 a;
        a[0] = (bf16_t)f0.x; a[1] = (bf16_t)f0.y; a[2] = (bf16_t)f0.z; a[3] = (bf16_t)f0.w;
        a[4] = (bf16_t)f1.x; a[5] = (bf16_t)f1.y; a[6] = (bf16_t)f1.z; a[7] = (bf16_t)f1.w;
        afr[ks] = a;
    }
    __syncthreads();   // all ctx reads in block retired before any write below

    const f32x4 zero = {0.f, 0.f, 0.f, 0.f};
    for (int nt = 0; nt < 16; ++nt) {
        const int ncol = nh * 256 + nt * 16 + c;
        const bf16_t* wrow = WoT + (size_t)ncol * 512;
        f32x4 a4 = zero;
#pragma unroll
        for (int ks = 0; ks < 16; ++ks) {
            const bf16x8 wf = *reinterpret_cast<const bf16x8*>(wrow + ks * 32 + g * 8);
            a4 = __builtin_amdgcn_mfma_f32_16x16x32_bf16(afr[ks], wf, a4, 0, 0, 0);
        }
        const float bval = bo[ncol];
#pragma unroll
        for (int i = 0; i < 4; ++i)
            out[(size_t)(row0 + 4 * g + i) * 512 + ncol] = a4[i] + bval;
    }
}

// ---------------------------------------------------------------------------
extern "C" void kernel_launch(void* const* d_in, const int* in_sizes, int n_in,
                              void* d_out, int out_size, void* d_ws, size_t ws_size,
                              hipStream_t stream) {
    const float* query = (const float*)d_in[0];
    const float* key_  = (const float*)d_in[1];
    const float* value = (const float*)d_in[2];
    const float* Wq = (const float*)d_in[3];
    const float* bq = (const float*)d_in[4];
    const float* Wk = (const float*)d_in[5];
    const float* bk = (const float*)d_in[6];
    const float* Wv = (const float*)d_in[7];
    const float* bv = (const float*)d_in[8];
    const float* Wo = (const float*)d_in[9];
    const float* bo = (const float*)d_in[10];

    char* wsb = (char*)d_ws;
    bf16_t* Qw   = (bf16_t*)(wsb);                     // 4 MB
    bf16_t* Kw   = (bf16_t*)(wsb + (4u << 20));        // 4 MB
    bf16_t* VTw  = (bf16_t*)(wsb + (8u << 20));        // 4 MB
    bf16_t* Wtq  = (bf16_t*)(wsb + (12u << 20));       // 512 KB
    bf16_t* Wtk  = Wtq + 8 * 64 * 512;                 // 512 KB
    bf16_t* Wtv  = Wtk + 8 * 64 * 512;                 // 512 KB
    bf16_t* WoTw = Wtv + 8 * 64 * 512;                 // 512 KB  (total 14 MB)

    prep_kernel<<<256, 256, 0, stream>>>(Wq, Wk, Wv, Wo, Wtq, Wtk, Wtv, WoTw);
    qkv_kernel<<<dim3(512, 3), 256, 0, stream>>>(query, key_, value,
                                                 Wtq, Wtk, Wtv, bq, bk, bv,
                                                 Qw, Kw, VTw);
    attn_kernel<<<256, 512, 0, stream>>>(Qw, Kw, VTw, (float*)d_out);
    out_proj_kernel<<<256, 128, 0, stream>>>((const float*)d_out, WoTw, bo, (float*)d_out);
}